// Round 1
// baseline (585.409 us; speedup 1.0000x reference)
//
#include <hip/hip_runtime.h>

// LangNN: fused 10-step LSTM encoder + 10-step LSTM decoder + actor head.
// B=131072 elements, H=25, A=18. fp32 throughout.
// One thread = one batch element; state (he,ce,hd,cd) in registers;
// weights staged in LDS (rows padded to 28 floats for ds_read_b128 merges).
// Encoder steps 1..9 use combined (W_ih+W_hh) since input == recurrent h.

#define HH 25
#define G4 100   // 4*H gate rows
#define PAD 28   // row padding: 28 floats = 112 B, keeps every row 16B-aligned
#define NSTEP 10
#define AOUT 18

__device__ __forceinline__ float frcp(float x) { return __builtin_amdgcn_rcpf(x); }
__device__ __forceinline__ float sigm(float x) { return frcp(1.0f + __expf(-x)); }
__device__ __forceinline__ float tanh_fast(float x) {
    float e = __expf(-2.0f * fabsf(x));
    float r = (1.0f - e) * frcp(1.0f + e);
    return copysignf(r, x);
}

__global__ __launch_bounds__(256, 2)
void langnn_kernel(const float* __restrict__ state,
                   const float* __restrict__ Wih_e, const float* __restrict__ Whh_e,
                   const float* __restrict__ bih_e, const float* __restrict__ bhh_e,
                   const float* __restrict__ Wih_d, const float* __restrict__ Whh_d,
                   const float* __restrict__ bih_d, const float* __restrict__ bhh_d,
                   const float* __restrict__ Wact, const float* __restrict__ bact,
                   float* __restrict__ out, int B)
{
    __shared__ float sWihE[G4][PAD];   // encoder W_ih (step 0 only)
    __shared__ float sWcE [G4][PAD];   // encoder W_ih + W_hh (steps 1..9)
    __shared__ float sWihD[G4][PAD];
    __shared__ float sWhhD[G4][PAD];
    __shared__ float sWA  [AOUT][PAD];
    __shared__ float sbE[G4], sbD[G4], sbA[AOUT];

    const int tid = threadIdx.x;
    for (int i = tid; i < G4 * HH; i += blockDim.x) {
        int r = i / HH, c = i % HH;
        float wie = Wih_e[i];
        sWihE[r][c] = wie;
        sWcE [r][c] = wie + Whh_e[i];
        sWihD[r][c] = Wih_d[i];
        sWhhD[r][c] = Whh_d[i];
    }
    for (int i = tid; i < AOUT * HH; i += blockDim.x) {
        int r = i / HH, c = i % HH;
        sWA[r][c] = Wact[i];
    }
    for (int i = tid; i < G4; i += blockDim.x) {
        sbE[i] = bih_e[i] + bhh_e[i];
        sbD[i] = bih_d[i] + bhh_d[i];
    }
    if (tid < AOUT) sbA[tid] = bact[tid];
    __syncthreads();

    const int b = blockIdx.x * blockDim.x + tid;
    if (b >= B) return;

    float he[HH], ce[HH], hd[HH], cd[HH], hn[HH];

    // he <- input state (x for encoder step 0)
    #pragma unroll
    for (int k = 0; k < HH; ++k) he[k] = state[(size_t)b * HH + k];

    float* encBase = out + (size_t)B * AOUT;

    // ---------------- t = 0 (peeled: h=c=0 for both cells) ----------------
    // encoder step 0: gates = x @ W_ih_e.T + b ; f-gate dead (c=0)
    #pragma unroll
    for (int j = 0; j < HH; ++j) {
        float ai = sbE[j], ag = sbE[2 * HH + j], ao = sbE[3 * HH + j];
        #pragma unroll
        for (int k = 0; k < HH; ++k) {
            float x = he[k];
            ai = fmaf(sWihE[j][k],          x, ai);
            ag = fmaf(sWihE[2 * HH + j][k], x, ag);
            ao = fmaf(sWihE[3 * HH + j][k], x, ao);
        }
        float cn = sigm(ai) * tanh_fast(ag);
        ce[j] = cn;
        hn[j] = sigm(ao) * tanh_fast(cn);
    }
    #pragma unroll
    for (int k = 0; k < HH; ++k) he[k] = hn[k];
    {
        float* ep = encBase + (size_t)b * HH;
        #pragma unroll
        for (int k = 0; k < HH; ++k) ep[k] = he[k];
    }
    // decoder step 0: x = he ; h=c=0 ; f-gate dead
    #pragma unroll
    for (int j = 0; j < HH; ++j) {
        float ai = sbD[j], ag = sbD[2 * HH + j], ao = sbD[3 * HH + j];
        #pragma unroll
        for (int k = 0; k < HH; ++k) {
            float x = he[k];
            ai = fmaf(sWihD[j][k],          x, ai);
            ag = fmaf(sWihD[2 * HH + j][k], x, ag);
            ao = fmaf(sWihD[3 * HH + j][k], x, ao);
        }
        float cn = sigm(ai) * tanh_fast(ag);
        cd[j] = cn;
        hd[j] = sigm(ao) * tanh_fast(cn);
    }

    // ---------------- t = 1..9 ----------------
    for (int t = 1; t < NSTEP; ++t) {
        // encoder: input == recurrent h -> combined weights
        #pragma unroll
        for (int j = 0; j < HH; ++j) {
            float ai = sbE[j], af = sbE[HH + j], ag = sbE[2 * HH + j], ao = sbE[3 * HH + j];
            #pragma unroll
            for (int k = 0; k < HH; ++k) {
                float x = he[k];
                ai = fmaf(sWcE[j][k],          x, ai);
                af = fmaf(sWcE[HH + j][k],     x, af);
                ag = fmaf(sWcE[2 * HH + j][k], x, ag);
                ao = fmaf(sWcE[3 * HH + j][k], x, ao);
            }
            float cn = sigm(af) * ce[j] + sigm(ai) * tanh_fast(ag);
            ce[j] = cn;
            hn[j] = sigm(ao) * tanh_fast(cn);
        }
        #pragma unroll
        for (int k = 0; k < HH; ++k) he[k] = hn[k];
        {
            float* ep = encBase + (size_t)t * B * HH + (size_t)b * HH;
            #pragma unroll
            for (int k = 0; k < HH; ++k) ep[k] = he[k];
        }
        // decoder: x = he (enc output of this step), recurrent hd
        #pragma unroll
        for (int j = 0; j < HH; ++j) {
            float ai = sbD[j], af = sbD[HH + j], ag = sbD[2 * HH + j], ao = sbD[3 * HH + j];
            #pragma unroll
            for (int k = 0; k < HH; ++k) {
                float x = he[k];
                float hv = hd[k];
                ai = fmaf(sWihD[j][k],          x, ai);
                ai = fmaf(sWhhD[j][k],          hv, ai);
                af = fmaf(sWihD[HH + j][k],     x, af);
                af = fmaf(sWhhD[HH + j][k],     hv, af);
                ag = fmaf(sWihD[2 * HH + j][k], x, ag);
                ag = fmaf(sWhhD[2 * HH + j][k], hv, ag);
                ao = fmaf(sWihD[3 * HH + j][k], x, ao);
                ao = fmaf(sWhhD[3 * HH + j][k], hv, ao);
            }
            float cn = sigm(af) * cd[j] + sigm(ai) * tanh_fast(ag);
            cd[j] = cn;
            hn[j] = sigm(ao) * tanh_fast(cn);
        }
        #pragma unroll
        for (int k = 0; k < HH; ++k) hd[k] = hn[k];
    }

    // ---------------- actor head ----------------
    #pragma unroll
    for (int a = 0; a < AOUT; ++a) {
        float acc = sbA[a];
        #pragma unroll
        for (int k = 0; k < HH; ++k) acc = fmaf(sWA[a][k], hd[k], acc);
        out[(size_t)b * AOUT + a] = acc;
    }
}

extern "C" void kernel_launch(void* const* d_in, const int* in_sizes, int n_in,
                              void* d_out, int out_size, void* d_ws, size_t ws_size,
                              hipStream_t stream) {
    const float* state = (const float*)d_in[0];
    const float* Wih_e = (const float*)d_in[1];
    const float* Whh_e = (const float*)d_in[2];
    const float* bih_e = (const float*)d_in[3];
    const float* bhh_e = (const float*)d_in[4];
    const float* Wih_d = (const float*)d_in[5];
    const float* Whh_d = (const float*)d_in[6];
    const float* bih_d = (const float*)d_in[7];
    const float* bhh_d = (const float*)d_in[8];
    const float* Wact  = (const float*)d_in[9];
    const float* bact  = (const float*)d_in[10];

    int B = in_sizes[0] / HH;
    int block = 256;
    int grid = (B + block - 1) / block;

    hipLaunchKernelGGL(langnn_kernel, dim3(grid), dim3(block), 0, stream,
                       state, Wih_e, Whh_e, bih_e, bhh_e,
                       Wih_d, Whh_d, bih_d, bhh_d, Wact, bact,
                       (float*)d_out, B);
}